// Round 14
// baseline (273.669 us; speedup 1.0000x reference)
//
#include <hip/hip_runtime.h>
#include <stdint.h>

#define ROUNDS 64
#define HIDDEN 256
#define BATCH  65536
#define NSUP   16   // super-rounds: 16 chains of 4 rounds each

typedef int   v4i  __attribute__((ext_vector_type(4)));
typedef int   v8i  __attribute__((ext_vector_type(8)));
typedef float v16f __attribute__((ext_vector_type(16)));
typedef unsigned long long u64;

// ============================================================================
// PARTIAL ALGEBRAIC COLLAPSE (math+packing verified exact R12/R13). Each round
// is affine over GF(2): s' = Whar s ^ n. 64 rounds -> 16 super-rounds of 4:
// M_g = W_{4g+3}..W_{4g}, c_g folded constant; then the PROVEN R3 batch kernel
// runs 16 rounds. R13 (207us) proved: intra-kernel cross-block sync costs
// ~100-150us (NEVER use it); launch boundaries ~20-25us each.
// R14: fuse bitpack INTO fold16 (block-local only): each of 16 blocks ballot-
// packs its OWN group's 4 matrices (1 MB) into LDS, composes LDS-sourced,
// packs. 2 launches total: foldpack16 -> hash16.
// ============================================================================

// ws layout (bytes)
#define WPK_OFF  0u        // fp4 A-frags [g=16][mt=8][ks=4][lane=64][16B] = 512 KB
#define NF_OFF   524288u   // noise floats [g=16][mt=8][lh=2][j=16] f32 = 16 KB

// sigma: nibble slot n (0..31) within a 32-k chunk holds logical k-offset
// rho(n). Applied identically to M-pack and state-pack so it cancels.
__host__ __device__ constexpr int rho(int n) {
  return 4 * (n >> 4) + (n & 3) + 8 * ((n >> 2) & 3);
}

// Per-C-slot bias (epilogue v_add_f32, IEEE-exact; round-1 FAILED note: bias
// must stay OUTSIDE the MFMA C-init; c in {0,1} as C-init is proven).
__host__ __device__ constexpr float bias_q(int q) {
  return (q == 0) ? 6291456.0f   // 1.5*2^22 -> parity at bit 1
       : (q == 1) ? 393216.0f    // 1.5*2^18 -> bit 5
       : (q == 2) ? 24576.0f     // 1.5*2^14 -> bit 9
                  : 1536.0f;     // 1.5*2^10 -> bit 13
}

// ---- 1) foldpack16: 16 INDEPENDENT blocks (zero cross-block anything).
// Block g: (a) ballot-packs rounds [4g,4g+4)'s W (1 MB, coalesced scalar
// loads, same bit mapping as the R9-proven bitpack) + noise into LDS;
// (b) 3 LDS-sourced composes (R8-R13-verified algorithm);
// (c) packs M_g -> fp4 A-fragments, c_g -> nf floats (R10-R13-verified). ----
__global__ __launch_bounds__(1024) void foldpack16(const float* __restrict__ mat,
                                                   const float* __restrict__ noi,
                                                   uint32_t* __restrict__ wpk,
                                                   float* __restrict__ nf) {
  __shared__ u64 WB[4][256][5];   // 40 KB, padded (b64 row reads: 4-way max)
  __shared__ u64 NBv[4][4];
  __shared__ u64 A[256][5];       // 10 KB, padded
  __shared__ u64 tbl[64][16][5];  // 40 KB
  __shared__ u64 avec[4];
  const int tid = threadIdx.x;
  const int g = blockIdx.x;  // chain/group 0..15
  const int w = tid >> 8;    // 0..3
  const int i = tid & 255;   // 0..255

  // (a) fused bitpack: 4 matrices = 262144 floats; wave (64 lanes) reads 64
  // consecutive floats of one row -> one ballot = one bit-word. e = element
  // index in the group slab: round e>>16, row (e>>8)&255, word (e>>6)&3.
  {
    const float* src = mat + (size_t)g * 262144;
#pragma unroll 8
    for (int it = 0; it < 256; ++it) {
      unsigned e = (unsigned)it * 1024u + (unsigned)tid;
      u64 m = __ballot(src[e] != 0.f);
      if ((tid & 63) == 0) WB[e >> 16][(e >> 8) & 255][(e >> 6) & 3] = m;
    }
    u64 m = __ballot(noi[(size_t)g * 1024 + tid] != 0.f);
    if ((tid & 63) == 0) NBv[tid >> 8][(tid >> 6) & 3] = m;
  }
  __syncthreads();

  // (b) compose the 4 maps: (A,a) <- (W_{4g+j}, n_{4g+j}) o (A,a), j=1..3.
  A[i][w] = WB[0][i][w];
  if (tid < 4) avec[tid] = NBv[0][tid];
  __syncthreads();

#pragma unroll
  for (int j = 1; j < 4; ++j) {
    const u64 br0 = WB[j][i][0], br1 = WB[j][i][1],
              br2 = WB[j][i][2], br3 = WB[j][i][3];
    const u64 bwc = NBv[j][i >> 6];
    const u64 av0 = avec[0], av1 = avec[1], av2 = avec[2], av3 = avec[3];

    // build 4-bit combination table over A's rows (contraction index k)
    {
      const int c = tid >> 4, m = tid & 15;  // 1024 entries, 1/thread
      u64 t0 = 0, t1 = 0, t2 = 0, t3 = 0;
#pragma unroll
      for (int jj = 0; jj < 4; ++jj)
        if (m & (1 << jj)) {
          t0 ^= A[4 * c + jj][0]; t1 ^= A[4 * c + jj][1];
          t2 ^= A[4 * c + jj][2]; t3 ^= A[4 * c + jj][3];
        }
      tbl[c][m][0] = t0; tbl[c][m][1] = t1; tbl[c][m][2] = t2; tbl[c][m][3] = t3;
    }
    __syncthreads();

    // R[i] = XOR_{k: B[i][k]=1} A[k], word w — 4-way ILP over the 64 gathers
    const u64 brr[4] = {br0, br1, br2, br3};  // constant-indexed under unroll
    u64 a0 = 0, a1 = 0, a2 = 0, a3 = 0;
#pragma unroll
    for (int c = 0; c < 64; c += 4) {
      unsigned n0 = (unsigned)(brr[(c + 0) >> 4] >> (((c + 0) & 15) * 4)) & 15u;
      unsigned n1 = (unsigned)(brr[(c + 1) >> 4] >> (((c + 1) & 15) * 4)) & 15u;
      unsigned n2 = (unsigned)(brr[(c + 2) >> 4] >> (((c + 2) & 15) * 4)) & 15u;
      unsigned n3 = (unsigned)(brr[(c + 3) >> 4] >> (((c + 3) & 15) * 4)) & 15u;
      a0 ^= tbl[c + 0][n0][w];
      a1 ^= tbl[c + 1][n1][w];
      a2 ^= tbl[c + 2][n2][w];
      a3 ^= tbl[c + 3][n3][w];
    }
    const u64 acc = (a0 ^ a1) ^ (a2 ^ a3);

    // a' = B*a ^ b : bit i = parity(popcount(Brow_i & a)) ^ b_i (waves 0..3)
    u64 mask = 0;
    if (tid < 256) {
      int p = __popcll(br0 & av0) + __popcll(br1 & av1) +
              __popcll(br2 & av2) + __popcll(br3 & av3);
      int bit = ((int)((bwc >> (i & 63)) & 1ull)) ^ (p & 1);
      mask = __ballot(bit);
    }
    __syncthreads();  // tbl/avec reads done before overwrite
    A[i][w] = acc;
    if (tid < 256 && (i & 63) == 0) avec[i >> 6] = mask;
    __syncthreads();
  }

  // (c) inline pack: M_g bits -> fp4 A-fragments, c_g -> nf floats
#pragma unroll
  for (int it = 0; it < 2; ++it) {
    unsigned tg = (unsigned)it * 1024u + tid;  // row*8 + kwin, 2048 total
    unsigned kwin = tg & 7u, row = tg >> 3;
    uint32_t wd[4] = {0, 0, 0, 0};
#pragma unroll
    for (int n = 0; n < 32; ++n) {
      int k = (int)kwin * 32 + rho(n);
      uint32_t bit = (uint32_t)((A[row][k >> 6] >> (k & 63)) & 1ull);
      wd[n >> 3] |= (bit * 2u) << ((n & 7) * 4);  // fp4 e2m1: +1 -> 0b0010
    }
    unsigned mt = row >> 5, lhh = kwin & 1u, ks = kwin >> 1;
    unsigned lane = lhh * 32u + (row & 31u);
    *(uint4*)(wpk + ((((unsigned)g * 32u + mt * 4u + ks) * 64u + lane) << 2)) =
        make_uint4(wd[0], wd[1], wd[2], wd[3]);
  }
  if (tid < 256) {  // nf[g][mt][lh][j] = c_g[row(j,lh,mt)]
    unsigned j = tid & 15u, lhh = (tid >> 4) & 1u, mt = (unsigned)tid >> 5;
    unsigned row = mt * 32u + (j & 3u) + 8u * (j >> 2) + 4u * lhh;
    nf[(unsigned)g * 256u + tid] = (float)((avec[row >> 6] >> (row & 63u)) & 1ull);
  }
}

// ---- 2) hash16: the PROVEN R3 hash4 structure, 16 super-rounds (R13: 70us).
// Per round: S <- parity(M_g S + c_g). fp4 MFMA 32x32x64, K=256 in 4 steps,
// c_g as MFMA C-init, bias-trick epilogue, double-buffered LDS state,
// round-ahead A/NZ prefetch. 512 thr, 128 el/block, wave wv = M-tile wv. ----
__global__ __launch_bounds__(512, 4) void hash16(const uint32_t* __restrict__ wpk,
                                                 const float* __restrict__ nf,
                                                 const float* __restrict__ sta,
                                                 float* __restrict__ out) {
  __shared__ uint8_t T[2][8][128][16];  // 32 KB
  const int t = threadIdx.x;
  const int wv = __builtin_amdgcn_readfirstlane(t >> 6);
  const int lane = t & 63;
  const int l31 = lane & 31;
  const int lh = lane >> 5;
  const int el0 = blockIdx.x * 128;

  // initial pack: f32 -> sigma-ordered fp4 nibbles into T[0]
#pragma unroll
  for (int i = 0; i < 16; ++i) {
    unsigned flat = (unsigned)i * 512u + t;
    unsigned el = flat >> 6, k4 = flat & 63u;
    float4 f = ((const float4*)(sta + (size_t)el0 * 256))[flat];
    uint32_t v = ((f.x != 0.f) ? 0x2u : 0u) | ((f.y != 0.f) ? 0x20u : 0u) |
                 ((f.z != 0.f) ? 0x200u : 0u) | ((f.w != 0.f) ? 0x2000u : 0u);
    unsigned KB = k4 >> 3, k4c = k4 & 7u;
    unsigned byteoff = (k4c & 1u) * 8u + 2u * (k4c >> 1);  // sigma^-1 of 4 rows
    *(uint16_t*)&T[0][KB][el][byteoff] = (uint16_t)v;
  }
  __syncthreads();

  // prefetch round-0 A fragments + c C-init
  v4i ap[4];
  {
    const uint32_t* wb = wpk + ((wv * 4) << 8);
#pragma unroll
    for (int ks = 0; ks < 4; ++ks) ap[ks] = *(const v4i*)(wb + ks * 256 + lane * 4);
  }
  v16f NZ = *(const v16f*)(nf + (wv * 2 + lh) * 16);

  for (int r = 0; r < NSUP; ++r) {
    const int rb = r & 1, nx = rb ^ 1;
    v16f acc[4];
    __builtin_amdgcn_s_setprio(1);
#pragma unroll
    for (int ks = 0; ks < 4; ++ks) {
      // fp4 fmt uses only regs 0..3 of the 8-reg operand: 4..7 stay undef.
      v8i A8 = __builtin_shufflevector(ap[ks], ap[ks], 0, 1, 2, 3, -1, -1, -1, -1);
      const int kb = 2 * ks + lh;
#pragma unroll
      for (int tn = 0; tn < 4; ++tn) {
        v4i b4 = *(const v4i*)&T[rb][kb][tn * 32 + l31][0];  // conflict-free b128
        v8i B8 = __builtin_shufflevector(b4, b4, 0, 1, 2, 3, -1, -1, -1, -1);
        acc[tn] = __builtin_amdgcn_mfma_scale_f32_32x32x64_f8f6f4(
            A8, B8, (ks == 0) ? NZ : acc[tn], 4, 4, 0, 127, 0, 127);
      }
    }
    __builtin_amdgcn_s_setprio(0);

    // prefetch next round's A + NZ (r=15 wraps to 0 -> no OOB, dead value)
    {
      const int rn = (r + 1) & (NSUP - 1);
      const uint32_t* wb = wpk + (((rn * 8 + wv) * 4) << 8);
#pragma unroll
      for (int ks = 0; ks < 4; ++ks) ap[ks] = *(const v4i*)(wb + ks * 256 + lane * 4);
      NZ = *(const v16f*)(nf + ((rn * 8 + wv) * 2 + lh) * 16);
    }

    // epilogue: per-slot bias (exact) puts slot j's parity bit at mantissa
    // bit 4*(j&3)+1 == its target nibble-bit; mask + or-chain.
#pragma unroll
    for (int tn = 0; tn < 4; ++tn) {
#define PB(j)                                                          \
  (__builtin_bit_cast(uint32_t, acc[tn][j] + bias_q((j) & 3)) &        \
   (2u << (4 * ((j) & 3))))
      uint32_t u0 = PB(0) | PB(1) | PB(2) | PB(3);
      uint32_t u1 = PB(4) | PB(5) | PB(6) | PB(7);
      uint32_t u2 = PB(8) | PB(9) | PB(10) | PB(11);
      uint32_t u3 = PB(12) | PB(13) | PB(14) | PB(15);
#undef PB
      *(uint2*)&T[nx][wv][tn * 32 + l31][lh * 8] =
          make_uint2(u0 | (u1 << 16), u2 | (u3 << 16));
    }

    __syncthreads();  // single barrier/round (double-buffered state)
  }

  // ---- final unpack: 16 rounds (even) -> buf 0 holds the output ----
#pragma unroll
  for (int i = 0; i < 16; ++i) {
    unsigned flat = (unsigned)i * 512u + t;
    unsigned el = flat >> 6, k4 = flat & 63u;
    unsigned KB = k4 >> 3, k4c = k4 & 7u;
    unsigned byteoff = (k4c & 1u) * 8u + 2u * (k4c >> 1);
    uint32_t v = *(const uint16_t*)&T[0][KB][el][byteoff];
    float4 o = make_float4((float)((v >> 1) & 1u), (float)((v >> 5) & 1u),
                           (float)((v >> 9) & 1u), (float)((v >> 13) & 1u));
    ((float4*)(out + (size_t)el0 * 256))[flat] = o;
  }
}

extern "C" void kernel_launch(void* const* d_in, const int* in_sizes, int n_in,
                              void* d_out, int out_size, void* d_ws, size_t ws_size,
                              hipStream_t stream) {
  const float* sta = (const float*)d_in[0];  // [B, HIDDEN]
  const float* mat = (const float*)d_in[1];  // [ROUNDS, HIDDEN, HIDDEN]
  const float* noi = (const float*)d_in[2];  // [ROUNDS, HIDDEN]
  uint8_t* wsb = (uint8_t*)d_ws;             // needs ~540 KB

  uint32_t* wpk = (uint32_t*)(wsb + WPK_OFF);
  float* nf     = (float*)(wsb + NF_OFF);

  foldpack16<<<16, 1024, 0, stream>>>(mat, noi, wpk, nf);
  hash16<<<512, 512, 0, stream>>>(wpk, nf, sta, (float*)d_out);
}

// Round 15
// 213.918 us; speedup vs baseline: 1.2793x; 1.2793x over previous
//
#include <hip/hip_runtime.h>
#include <stdint.h>

#define ROUNDS 64
#define HIDDEN 256
#define BATCH  65536
#define NSUP   16   // super-rounds: 16 chains of 4 rounds each

typedef int   v4i  __attribute__((ext_vector_type(4)));
typedef int   v8i  __attribute__((ext_vector_type(8)));
typedef float v16f __attribute__((ext_vector_type(16)));
typedef unsigned long long u64;

// ============================================================================
// PARTIAL ALGEBRAIC COLLAPSE (math+packing verified exact R12-R14). Each round
// is affine over GF(2): s' = Whar s ^ n. 64 rounds -> 16 super-rounds of 4:
// M_g = W_{4g+3}..W_{4g}, c_g folded constant; then the PROVEN R3 batch kernel
// runs 16 rounds. Proven stack facts: intra-kernel cross-block sync costs
// ~100-150us (NEVER); launch boundary ~20-25us; R14's fused bitpack was
// serialized by per-iteration load->ballot chains (~96us exposed latency).
// R15: bitpack with full MLP — each thread builds ONE u64 word from 64
// consecutive floats via 16 independent float4 loads (no cross-lane ops, no
// load->ballot chain). 2 launches: foldpack16 -> hash16.
// ============================================================================

// ws layout (bytes)
#define WPK_OFF  0u        // fp4 A-frags [g=16][mt=8][ks=4][lane=64][16B] = 512 KB
#define NF_OFF   524288u   // noise floats [g=16][mt=8][lh=2][j=16] f32 = 16 KB

// sigma: nibble slot n (0..31) within a 32-k chunk holds logical k-offset
// rho(n). Applied identically to M-pack and state-pack so it cancels.
__host__ __device__ constexpr int rho(int n) {
  return 4 * (n >> 4) + (n & 3) + 8 * ((n >> 2) & 3);
}

// Per-C-slot bias (epilogue v_add_f32, IEEE-exact; round-1 FAILED note: bias
// must stay OUTSIDE the MFMA C-init; c in {0,1} as C-init is proven).
__host__ __device__ constexpr float bias_q(int q) {
  return (q == 0) ? 6291456.0f   // 1.5*2^22 -> parity at bit 1
       : (q == 1) ? 393216.0f    // 1.5*2^18 -> bit 5
       : (q == 2) ? 24576.0f     // 1.5*2^14 -> bit 9
                  : 1536.0f;     // 1.5*2^10 -> bit 13
}

// ---- 1) foldpack16: 16 INDEPENDENT blocks (zero cross-block anything).
// Block g: (a) packs rounds [4g,4g+4)'s W (1 MB) into LDS bit-matrices with
// full memory-level parallelism; (b) 3 LDS-sourced composes (R8-R14-verified);
// (c) packs M_g -> fp4 A-fragments, c_g -> nf floats (R10-R14-verified). ----
__global__ __launch_bounds__(1024) void foldpack16(const float* __restrict__ mat,
                                                   const float* __restrict__ noi,
                                                   uint32_t* __restrict__ wpk,
                                                   float* __restrict__ nf) {
  __shared__ u64 WB[4][256][5];   // 40 KB, padded (b64 row reads: 4-way max)
  __shared__ u64 NBv[4][4];
  __shared__ u64 A[256][5];       // 10 KB, padded
  __shared__ u64 tbl[64][16][5];  // 40 KB
  __shared__ u64 avec[4];
  const int tid = threadIdx.x;
  const int g = blockIdx.x;  // chain/group 0..15
  const int w = tid >> 8;    // 0..3
  const int i = tid & 255;   // 0..255

  // (a) MLP bitpack: thread tid builds u64 word tid of matrix j entirely
  // locally: floats [j*65536 + tid*64, +64) = 16 independent float4 loads.
  // Word w of row i holds bits k = 64w..64w+63 (same mapping as R9-R13).
  {
#pragma unroll 1  // keep f[16] (64 VGPR) from being 4x-unrolled into spills
    for (int j = 0; j < 4; ++j) {
      const float4* s4 =
          (const float4*)(mat + (size_t)g * 262144 + (size_t)j * 65536) +
          (size_t)tid * 16;
      float4 f[16];
#pragma unroll
      for (int q = 0; q < 16; ++q) f[q] = s4[q];  // all 16 in flight
      u64 bits = 0;
#pragma unroll
      for (int q = 0; q < 16; ++q) {
        bits |= (u64)(f[q].x != 0.f ? 1u : 0u) << (4 * q + 0);
        bits |= (u64)(f[q].y != 0.f ? 1u : 0u) << (4 * q + 1);
        bits |= (u64)(f[q].z != 0.f ? 1u : 0u) << (4 * q + 2);
        bits |= (u64)(f[q].w != 0.f ? 1u : 0u) << (4 * q + 3);
      }
      WB[j][tid >> 2][tid & 3] = bits;
    }
    // noise: 1024 floats, single load + single ballot per wave (no chain)
    u64 m = __ballot(noi[(size_t)g * 1024 + tid] != 0.f);
    if ((tid & 63) == 0) NBv[tid >> 8][(tid >> 6) & 3] = m;
  }
  __syncthreads();

  // (b) compose the 4 maps: (A,a) <- (W_{4g+j}, n_{4g+j}) o (A,a), j=1..3.
  A[i][w] = WB[0][i][w];
  if (tid < 4) avec[tid] = NBv[0][tid];
  __syncthreads();

#pragma unroll
  for (int j = 1; j < 4; ++j) {
    const u64 br0 = WB[j][i][0], br1 = WB[j][i][1],
              br2 = WB[j][i][2], br3 = WB[j][i][3];
    const u64 bwc = NBv[j][i >> 6];
    const u64 av0 = avec[0], av1 = avec[1], av2 = avec[2], av3 = avec[3];

    // build 4-bit combination table over A's rows (contraction index k)
    {
      const int c = tid >> 4, m = tid & 15;  // 1024 entries, 1/thread
      u64 t0 = 0, t1 = 0, t2 = 0, t3 = 0;
#pragma unroll
      for (int jj = 0; jj < 4; ++jj)
        if (m & (1 << jj)) {
          t0 ^= A[4 * c + jj][0]; t1 ^= A[4 * c + jj][1];
          t2 ^= A[4 * c + jj][2]; t3 ^= A[4 * c + jj][3];
        }
      tbl[c][m][0] = t0; tbl[c][m][1] = t1; tbl[c][m][2] = t2; tbl[c][m][3] = t3;
    }
    __syncthreads();

    // R[i] = XOR_{k: B[i][k]=1} A[k], word w — 4-way ILP over the 64 gathers
    const u64 brr[4] = {br0, br1, br2, br3};  // constant-indexed under unroll
    u64 a0 = 0, a1 = 0, a2 = 0, a3 = 0;
#pragma unroll
    for (int c = 0; c < 64; c += 4) {
      unsigned n0 = (unsigned)(brr[(c + 0) >> 4] >> (((c + 0) & 15) * 4)) & 15u;
      unsigned n1 = (unsigned)(brr[(c + 1) >> 4] >> (((c + 1) & 15) * 4)) & 15u;
      unsigned n2 = (unsigned)(brr[(c + 2) >> 4] >> (((c + 2) & 15) * 4)) & 15u;
      unsigned n3 = (unsigned)(brr[(c + 3) >> 4] >> (((c + 3) & 15) * 4)) & 15u;
      a0 ^= tbl[c + 0][n0][w];
      a1 ^= tbl[c + 1][n1][w];
      a2 ^= tbl[c + 2][n2][w];
      a3 ^= tbl[c + 3][n3][w];
    }
    const u64 acc = (a0 ^ a1) ^ (a2 ^ a3);

    // a' = B*a ^ b : bit i = parity(popcount(Brow_i & a)) ^ b_i (waves 0..3)
    u64 mask = 0;
    if (tid < 256) {
      int p = __popcll(br0 & av0) + __popcll(br1 & av1) +
              __popcll(br2 & av2) + __popcll(br3 & av3);
      int bit = ((int)((bwc >> (i & 63)) & 1ull)) ^ (p & 1);
      mask = __ballot(bit);
    }
    __syncthreads();  // tbl/avec reads done before overwrite
    A[i][w] = acc;
    if (tid < 256 && (i & 63) == 0) avec[i >> 6] = mask;
    __syncthreads();
  }

  // (c) inline pack: M_g bits -> fp4 A-fragments, c_g -> nf floats
#pragma unroll
  for (int it = 0; it < 2; ++it) {
    unsigned tg = (unsigned)it * 1024u + tid;  // row*8 + kwin, 2048 total
    unsigned kwin = tg & 7u, row = tg >> 3;
    uint32_t wd[4] = {0, 0, 0, 0};
#pragma unroll
    for (int n = 0; n < 32; ++n) {
      int k = (int)kwin * 32 + rho(n);
      uint32_t bit = (uint32_t)((A[row][k >> 6] >> (k & 63)) & 1ull);
      wd[n >> 3] |= (bit * 2u) << ((n & 7) * 4);  // fp4 e2m1: +1 -> 0b0010
    }
    unsigned mt = row >> 5, lhh = kwin & 1u, ks = kwin >> 1;
    unsigned lane = lhh * 32u + (row & 31u);
    *(uint4*)(wpk + ((((unsigned)g * 32u + mt * 4u + ks) * 64u + lane) << 2)) =
        make_uint4(wd[0], wd[1], wd[2], wd[3]);
  }
  if (tid < 256) {  // nf[g][mt][lh][j] = c_g[row(j,lh,mt)]
    unsigned j = tid & 15u, lhh = (tid >> 4) & 1u, mt = (unsigned)tid >> 5;
    unsigned row = mt * 32u + (j & 3u) + 8u * (j >> 2) + 4u * lhh;
    nf[(unsigned)g * 256u + tid] = (float)((avec[row >> 6] >> (row & 63u)) & 1ull);
  }
}

// ---- 2) hash16: the PROVEN R3 hash4 structure, 16 super-rounds (R13: 70us).
// Per round: S <- parity(M_g S + c_g). fp4 MFMA 32x32x64, K=256 in 4 steps,
// c_g as MFMA C-init, bias-trick epilogue, double-buffered LDS state,
// round-ahead A/NZ prefetch. 512 thr, 128 el/block, wave wv = M-tile wv. ----
__global__ __launch_bounds__(512, 4) void hash16(const uint32_t* __restrict__ wpk,
                                                 const float* __restrict__ nf,
                                                 const float* __restrict__ sta,
                                                 float* __restrict__ out) {
  __shared__ uint8_t T[2][8][128][16];  // 32 KB
  const int t = threadIdx.x;
  const int wv = __builtin_amdgcn_readfirstlane(t >> 6);
  const int lane = t & 63;
  const int l31 = lane & 31;
  const int lh = lane >> 5;
  const int el0 = blockIdx.x * 128;

  // initial pack: f32 -> sigma-ordered fp4 nibbles into T[0]
#pragma unroll
  for (int i = 0; i < 16; ++i) {
    unsigned flat = (unsigned)i * 512u + t;
    unsigned el = flat >> 6, k4 = flat & 63u;
    float4 f = ((const float4*)(sta + (size_t)el0 * 256))[flat];
    uint32_t v = ((f.x != 0.f) ? 0x2u : 0u) | ((f.y != 0.f) ? 0x20u : 0u) |
                 ((f.z != 0.f) ? 0x200u : 0u) | ((f.w != 0.f) ? 0x2000u : 0u);
    unsigned KB = k4 >> 3, k4c = k4 & 7u;
    unsigned byteoff = (k4c & 1u) * 8u + 2u * (k4c >> 1);  // sigma^-1 of 4 rows
    *(uint16_t*)&T[0][KB][el][byteoff] = (uint16_t)v;
  }
  __syncthreads();

  // prefetch round-0 A fragments + c C-init
  v4i ap[4];
  {
    const uint32_t* wb = wpk + ((wv * 4) << 8);
#pragma unroll
    for (int ks = 0; ks < 4; ++ks) ap[ks] = *(const v4i*)(wb + ks * 256 + lane * 4);
  }
  v16f NZ = *(const v16f*)(nf + (wv * 2 + lh) * 16);

  for (int r = 0; r < NSUP; ++r) {
    const int rb = r & 1, nx = rb ^ 1;
    v16f acc[4];
    __builtin_amdgcn_s_setprio(1);
#pragma unroll
    for (int ks = 0; ks < 4; ++ks) {
      // fp4 fmt uses only regs 0..3 of the 8-reg operand: 4..7 stay undef.
      v8i A8 = __builtin_shufflevector(ap[ks], ap[ks], 0, 1, 2, 3, -1, -1, -1, -1);
      const int kb = 2 * ks + lh;
#pragma unroll
      for (int tn = 0; tn < 4; ++tn) {
        v4i b4 = *(const v4i*)&T[rb][kb][tn * 32 + l31][0];  // conflict-free b128
        v8i B8 = __builtin_shufflevector(b4, b4, 0, 1, 2, 3, -1, -1, -1, -1);
        acc[tn] = __builtin_amdgcn_mfma_scale_f32_32x32x64_f8f6f4(
            A8, B8, (ks == 0) ? NZ : acc[tn], 4, 4, 0, 127, 0, 127);
      }
    }
    __builtin_amdgcn_s_setprio(0);

    // prefetch next round's A + NZ (r=15 wraps to 0 -> no OOB, dead value)
    {
      const int rn = (r + 1) & (NSUP - 1);
      const uint32_t* wb = wpk + (((rn * 8 + wv) * 4) << 8);
#pragma unroll
      for (int ks = 0; ks < 4; ++ks) ap[ks] = *(const v4i*)(wb + ks * 256 + lane * 4);
      NZ = *(const v16f*)(nf + ((rn * 8 + wv) * 2 + lh) * 16);
    }

    // epilogue: per-slot bias (exact) puts slot j's parity bit at mantissa
    // bit 4*(j&3)+1 == its target nibble-bit; mask + or-chain.
#pragma unroll
    for (int tn = 0; tn < 4; ++tn) {
#define PB(j)                                                          \
  (__builtin_bit_cast(uint32_t, acc[tn][j] + bias_q((j) & 3)) &        \
   (2u << (4 * ((j) & 3))))
      uint32_t u0 = PB(0) | PB(1) | PB(2) | PB(3);
      uint32_t u1 = PB(4) | PB(5) | PB(6) | PB(7);
      uint32_t u2 = PB(8) | PB(9) | PB(10) | PB(11);
      uint32_t u3 = PB(12) | PB(13) | PB(14) | PB(15);
#undef PB
      *(uint2*)&T[nx][wv][tn * 32 + l31][lh * 8] =
          make_uint2(u0 | (u1 << 16), u2 | (u3 << 16));
    }

    __syncthreads();  // single barrier/round (double-buffered state)
  }

  // ---- final unpack: 16 rounds (even) -> buf 0 holds the output ----
#pragma unroll
  for (int i = 0; i < 16; ++i) {
    unsigned flat = (unsigned)i * 512u + t;
    unsigned el = flat >> 6, k4 = flat & 63u;
    unsigned KB = k4 >> 3, k4c = k4 & 7u;
    unsigned byteoff = (k4c & 1u) * 8u + 2u * (k4c >> 1);
    uint32_t v = *(const uint16_t*)&T[0][KB][el][byteoff];
    float4 o = make_float4((float)((v >> 1) & 1u), (float)((v >> 5) & 1u),
                           (float)((v >> 9) & 1u), (float)((v >> 13) & 1u));
    ((float4*)(out + (size_t)el0 * 256))[flat] = o;
  }
}

extern "C" void kernel_launch(void* const* d_in, const int* in_sizes, int n_in,
                              void* d_out, int out_size, void* d_ws, size_t ws_size,
                              hipStream_t stream) {
  const float* sta = (const float*)d_in[0];  // [B, HIDDEN]
  const float* mat = (const float*)d_in[1];  // [ROUNDS, HIDDEN, HIDDEN]
  const float* noi = (const float*)d_in[2];  // [ROUNDS, HIDDEN]
  uint8_t* wsb = (uint8_t*)d_ws;             // needs ~540 KB

  uint32_t* wpk = (uint32_t*)(wsb + WPK_OFF);
  float* nf     = (float*)(wsb + NF_OFF);

  foldpack16<<<16, 1024, 0, stream>>>(mat, noi, wpk, nf);
  hash16<<<512, 512, 0, stream>>>(wpk, nf, sta, (float*)d_out);
}